// Round 5
// baseline (2547.696 us; speedup 1.0000x reference)
//
#include <hip/hip_runtime.h>
#include <hip/hip_bf16.h>
#include <math.h>

#define BB 8
#define DD 256
#define LL 2048
#define KK 24
#define RR 1025
#define HH 512

// ---------------- LayerNorm over channel dim D, per (b,l) ----------------
__global__ void ln_kernel(const float* __restrict__ x, const float* __restrict__ gamma,
                          const float* __restrict__ beta, float* __restrict__ z) {
  __shared__ float red[2][4][64];
  __shared__ float mu_s[64], rs_s[64];
  int blk = blockIdx.x;
  int b = blk >> 5;            // / (L/64 = 32)
  int l0 = (blk & 31) << 6;
  int t = threadIdx.x;
  int ll = t & 63;
  int part = t >> 6;           // 0..3, each covers 64 d's
  int l = l0 + ll;
  const float* xb = x + ((size_t)b * DD) * LL + l;
  float xv[64];
  float s = 0.f, ss = 0.f;
  #pragma unroll
  for (int i = 0; i < 64; ++i) {
    float v = xb[(size_t)(part * 64 + i) * LL];
    xv[i] = v; s += v; ss += v * v;
  }
  red[0][part][ll] = s; red[1][part][ll] = ss;
  __syncthreads();
  if (part == 0) {
    float S = red[0][0][ll] + red[0][1][ll] + red[0][2][ll] + red[0][3][ll];
    float Q = red[1][0][ll] + red[1][1][ll] + red[1][2][ll] + red[1][3][ll];
    float mu = S * (1.f / 256.f);
    float var = Q * (1.f / 256.f) - mu * mu;
    mu_s[ll] = mu; rs_s[ll] = rsqrtf(var + 1e-5f);
  }
  __syncthreads();
  float mu = mu_s[ll], rs = rs_s[ll];
  float* zb = z + ((size_t)b * DD) * LL + l;
  #pragma unroll
  for (int i = 0; i < 64; ++i) {
    int d = part * 64 + i;
    zb[(size_t)d * LL] = (xv[i] - mu) * rs * gamma[d] + beta[d];
  }
}

// ---------------- generic 32x32 tiled transpose, batched ----------------
__global__ void transpose_kernel(const float* __restrict__ src, float* __restrict__ dst,
                                 int rows, int cols) {
  __shared__ float tile[32][33];
  int mat = blockIdx.z;
  const float* s = src + (size_t)mat * rows * cols;
  float* d = dst + (size_t)mat * rows * cols;
  int c0 = blockIdx.x * 32, r0 = blockIdx.y * 32;
  for (int i = threadIdx.y; i < 32; i += 8)
    tile[i][threadIdx.x] = s[(size_t)(r0 + i) * cols + c0 + threadIdx.x];
  __syncthreads();
  for (int i = threadIdx.y; i < 32; i += 8)
    d[(size_t)(c0 + i) * rows + r0 + threadIdx.x] = tile[threadIdx.x][i];
}

// ---------------- Stockham radix-2 FFT, n=2048, in LDS ----------------
__device__ __forceinline__ float2* fft2048(float2* bufA, float2* bufB,
                                           const float2* __restrict__ tw, int t) {
  float2* src = bufA; float2* dst = bufB;
  for (int stage = 0; stage < 11; ++stage) {
    int s = 1 << stage;
    #pragma unroll
    for (int j = 0; j < 4; ++j) {
      int idx = t + 256 * j;           // 0..1023
      int q = idx & (s - 1);
      int p = idx >> stage;
      float2 a = src[idx];
      float2 b = src[idx + 1024];
      float sr = a.x + b.x, si = a.y + b.y;
      float dr = a.x - b.x, di = a.y - b.y;
      float2 w = tw[p << stage];       // (cos, -sin)
      dst[q + 2 * s * p] = make_float2(sr, si);
      dst[q + 2 * s * p + s] = make_float2(dr * w.x - di * w.y, dr * w.y + di * w.x);
    }
    __syncthreads();
    float2* tmp = src; src = dst; dst = tmp;
  }
  return src;
}

__device__ __forceinline__ void build_tw(float2* tw, int t) {
  #pragma unroll
  for (int j = 0; j < 4; ++j) {
    int i = t + 256 * j;
    float xfrac = (float)i * (1.f / 1024.f);
    tw[i] = make_float2(cospif(xfrac), -sinpif(xfrac));
  }
}

__global__ void rfft_kernel(const float* __restrict__ z, float2* __restrict__ Xf) {
  __shared__ float2 bufA[2048];
  __shared__ float2 bufB[2048];
  __shared__ float2 tw[1024];
  int row = blockIdx.x;            // b*D + d
  int t = threadIdx.x;
  build_tw(tw, t);
  const float* zr = z + (size_t)row * LL;
  #pragma unroll
  for (int j = 0; j < 8; ++j) {
    int i = t + 256 * j;
    bufA[i] = make_float2(zr[i], 0.f);
  }
  __syncthreads();
  float2* res = fft2048(bufA, bufB, tw, t);
  #pragma unroll
  for (int j = 0; j < 5; ++j) {
    int r = t + 256 * j;
    if (r <= 1024) Xf[(size_t)row * RR + r] = res[r];
  }
}

// irfft(F, n=2048) = real( fft( conj(F_full) ) ) / 2048
__global__ void irfft_kernel(const float2* __restrict__ Sf, float* __restrict__ S) {
  __shared__ float2 bufA[2048];
  __shared__ float2 bufB[2048];
  __shared__ float2 tw[1024];
  int row = blockIdx.x;            // b*D + h
  int t = threadIdx.x;
  build_tw(tw, t);
  const float2* fr = Sf + (size_t)row * RR;
  #pragma unroll
  for (int j = 0; j < 8; ++j) {
    int i = t + 256 * j;
    float2 v;
    if (i <= 1024) { v = fr[i]; v.y = -v.y; }   // conj(F[i])
    else           { v = fr[2048 - i]; }        // F[2048-i]
    bufA[i] = v;
  }
  __syncthreads();
  float2* res = fft2048(bufA, bufB, tw, t);
  const float scale = 1.f / 2048.f;
  float* sr = S + (size_t)row * LL;
  #pragma unroll
  for (int j = 0; j < 8; ++j) {
    int i = t + 256 * j;
    sr[i] = res[i].x * scale;
  }
}

// ---------------- spectral mixing ----------------
// Sf[b,h,r] = sum_d Xf[b,d,r] * M[d,h,r],  M = sum_k Theta[k,h,d]*(Phi_re - i Phi_im)[k,r]
// One thread per (r, h): grid (129 r-tiles of 8, 8 h-tiles of 32), 256 thr.
__global__ void spectral_kernel(const float2* __restrict__ Xf,
                                const float* __restrict__ ThT,   // [K][d][h]
                                const float* __restrict__ Phi_re,
                                const float* __restrict__ Phi_im,
                                float2* __restrict__ Sf) {
  __shared__ float2 xs[BB][64][8];
  int t = threadIdx.x;
  int rl = t & 7;
  int r0 = blockIdx.x << 3;
  int h = (blockIdx.y << 5) + (t >> 3);
  int r = r0 + rl;
  int rc = min(r, RR - 1);
  float phr[KK], phim[KK];
  #pragma unroll
  for (int k = 0; k < KK; ++k) {
    phr[k]  = Phi_re[k * RR + rc];
    phim[k] = Phi_im[k * RR + rc];
  }
  float ar[BB], ai[BB];
  #pragma unroll
  for (int b = 0; b < BB; ++b) { ar[b] = 0.f; ai[b] = 0.f; }

  for (int dc = 0; dc < DD; dc += 64) {
    __syncthreads();
    #pragma unroll
    for (int j = 0; j < 16; ++j) {
      int i = t + 256 * j;          // 0..4095
      int b = i >> 9;
      int dl = (i >> 3) & 63;
      int rr = i & 7;
      xs[b][dl][rr] = Xf[((size_t)(b * DD + dc + dl)) * RR + min(r0 + rr, RR - 1)];
    }
    __syncthreads();
    for (int dl = 0; dl < 64; ++dl) {
      int d = dc + dl;
      const float* tp = ThT + (size_t)d * DD + h;
      float mre = 0.f, mim = 0.f;
      #pragma unroll
      for (int k = 0; k < KK; ++k) {
        float th = tp[(size_t)k * DD * DD];
        mre += th * phr[k];
        mim -= th * phim[k];
      }
      #pragma unroll
      for (int b = 0; b < BB; ++b) {
        float2 xv = xs[b][dl][rl];
        ar[b] += xv.x * mre - xv.y * mim;
        ai[b] += xv.x * mim + xv.y * mre;
      }
    }
  }
  if (r < RR) {
    #pragma unroll
    for (int b = 0; b < BB; ++b) {
      Sf[((size_t)(b * DD + h)) * RR + r] = make_float2(ar[b], ai[b]);
    }
  }
}

// ---------------- fused MLP + residual, f32 output ----------------
__global__ void mlp_kernel(const float* __restrict__ S, const float* __restrict__ x,
                           const float* __restrict__ W1T, const float* __restrict__ b1,
                           const float* __restrict__ W2T, const float* __restrict__ b2,
                           float* __restrict__ out) {
  __shared__ float s_s[DD][32];
  __shared__ float h_s[128][36];
  int b = blockIdx.y;
  int l0 = blockIdx.x << 5;
  int t = threadIdx.x;
  {
    const float* Sp = S + ((size_t)(b * DD + t)) * LL + l0;
    float4* drow = reinterpret_cast<float4*>(&s_s[t][0]);
    const float4* srow = reinterpret_cast<const float4*>(Sp);
    #pragma unroll
    for (int j = 0; j < 8; ++j) drow[j] = srow[j];
  }
  int h_loc = t >> 1;
  int lhalf = t & 1;
  float acc[32];
  #pragma unroll
  for (int i = 0; i < 32; ++i) acc[i] = 0.f;

  for (int hcBase = 0; hcBase < HH; hcBase += 128) {
    __syncthreads();
    int h = hcBase + h_loc;
    float a[16];
    float bias = b1[h];
    #pragma unroll
    for (int i = 0; i < 16; ++i) a[i] = bias;
    for (int c = 0; c < DD; ++c) {
      float w = W1T[(size_t)c * HH + h];
      const float4* sv4 = reinterpret_cast<const float4*>(&s_s[c][lhalf * 16]);
      #pragma unroll
      for (int j = 0; j < 4; ++j) {
        float4 sv = sv4[j];
        a[j * 4 + 0] += w * sv.x; a[j * 4 + 1] += w * sv.y;
        a[j * 4 + 2] += w * sv.z; a[j * 4 + 3] += w * sv.w;
      }
    }
    #pragma unroll
    for (int i = 0; i < 16; ++i) {
      float v = a[i];
      h_s[h_loc][lhalf * 16 + i] = 0.5f * v * (1.f + erff(v * 0.70710678118654752f));
    }
    __syncthreads();
    for (int hh = 0; hh < 128; ++hh) {
      float w = W2T[(size_t)(hcBase + hh) * DD + t];
      const float4* hv4 = reinterpret_cast<const float4*>(&h_s[hh][0]);
      #pragma unroll
      for (int j = 0; j < 8; ++j) {
        float4 hv = hv4[j];
        acc[j * 4 + 0] += w * hv.x; acc[j * 4 + 1] += w * hv.y;
        acc[j * 4 + 2] += w * hv.z; acc[j * 4 + 3] += w * hv.w;
      }
    }
  }
  const float* xp = x + ((size_t)(b * DD + t)) * LL + l0;
  float* op = out + ((size_t)(b * DD + t)) * LL + l0;
  float bb2 = b2[t];
  #pragma unroll
  for (int j = 0; j < 8; ++j) {
    float4 xv = reinterpret_cast<const float4*>(xp)[j];
    float4 o;
    o.x = xv.x + bb2 + acc[j * 4 + 0];
    o.y = xv.y + bb2 + acc[j * 4 + 1];
    o.z = xv.z + bb2 + acc[j * 4 + 2];
    o.w = xv.w + bb2 + acc[j * 4 + 3];
    reinterpret_cast<float4*>(op)[j] = o;
  }
}

extern "C" void kernel_launch(void* const* d_in, const int* in_sizes, int n_in,
                              void* d_out, int out_size, void* d_ws, size_t ws_size,
                              hipStream_t stream) {
  const float* x      = (const float*)d_in[0];
  const float* Phi_re = (const float*)d_in[1];
  const float* Phi_im = (const float*)d_in[2];
  const float* Theta  = (const float*)d_in[3];
  const float* gamma  = (const float*)d_in[4];
  const float* beta   = (const float*)d_in[5];
  const float* W1     = (const float*)d_in[6];
  const float* b1     = (const float*)d_in[7];
  const float* W2     = (const float*)d_in[8];
  const float* b2     = (const float*)d_in[9];

  float* ws = (float*)d_ws;
  float*  z   = ws;                          // 4,194,304 floats (reused for S)
  float2* Xf  = (float2*)(ws + 4194304);     // 2,099,200 float2
  float2* Sf  = (float2*)(ws + 8392704);     // 2,099,200 float2
  float*  ThT = ws + 12591104;               // 1,572,864
  float*  W1T = ws + 14163968;               // 131,072
  float*  W2T = ws + 14295040;               // 131,072

  ln_kernel<<<dim3(BB * (LL / 64)), 256, 0, stream>>>(x, gamma, beta, z);
  transpose_kernel<<<dim3(8, 8, 24), dim3(32, 8), 0, stream>>>(Theta, ThT, 256, 256);
  transpose_kernel<<<dim3(8, 16, 1), dim3(32, 8), 0, stream>>>(W1, W1T, 512, 256);
  transpose_kernel<<<dim3(16, 8, 1), dim3(32, 8), 0, stream>>>(W2, W2T, 256, 512);
  rfft_kernel<<<dim3(BB * DD), 256, 0, stream>>>(z, Xf);
  spectral_kernel<<<dim3(129, 8), 256, 0, stream>>>(Xf, ThT, Phi_re, Phi_im, Sf);
  irfft_kernel<<<dim3(BB * DD), 256, 0, stream>>>(Sf, z);      // S -> z buffer
  mlp_kernel<<<dim3(LL / 32, BB), 256, 0, stream>>>(z, x, W1T, b1, W2T, b2,
                                                    (float*)d_out);
}

// Round 6
// 769.706 us; speedup vs baseline: 3.3100x; 3.3100x over previous
//
#include <hip/hip_runtime.h>
#include <hip/hip_bf16.h>
#include <math.h>

#define BB 8
#define DD 256
#define LL 2048
#define KK 24
#define RR 1025
#define HH 512

// ---------------- LayerNorm over channel dim D, per (b,l) ----------------
__global__ void ln_kernel(const float* __restrict__ x, const float* __restrict__ gamma,
                          const float* __restrict__ beta, float* __restrict__ z) {
  __shared__ float red[2][4][64];
  __shared__ float mu_s[64], rs_s[64];
  int blk = blockIdx.x;
  int b = blk >> 5;            // / (L/64 = 32)
  int l0 = (blk & 31) << 6;
  int t = threadIdx.x;
  int ll = t & 63;
  int part = t >> 6;           // 0..3, each covers 64 d's
  int l = l0 + ll;
  const float* xb = x + ((size_t)b * DD) * LL + l;
  float xv[64];
  float s = 0.f, ss = 0.f;
  #pragma unroll
  for (int i = 0; i < 64; ++i) {
    float v = xb[(size_t)(part * 64 + i) * LL];
    xv[i] = v; s += v; ss += v * v;
  }
  red[0][part][ll] = s; red[1][part][ll] = ss;
  __syncthreads();
  if (part == 0) {
    float S = red[0][0][ll] + red[0][1][ll] + red[0][2][ll] + red[0][3][ll];
    float Q = red[1][0][ll] + red[1][1][ll] + red[1][2][ll] + red[1][3][ll];
    float mu = S * (1.f / 256.f);
    float var = Q * (1.f / 256.f) - mu * mu;
    mu_s[ll] = mu; rs_s[ll] = rsqrtf(var + 1e-5f);
  }
  __syncthreads();
  float mu = mu_s[ll], rs = rs_s[ll];
  float* zb = z + ((size_t)b * DD) * LL + l;
  #pragma unroll
  for (int i = 0; i < 64; ++i) {
    int d = part * 64 + i;
    zb[(size_t)d * LL] = (xv[i] - mu) * rs * gamma[d] + beta[d];
  }
}

// ---------------- generic 32x32 tiled transpose, batched ----------------
__global__ void transpose_kernel(const float* __restrict__ src, float* __restrict__ dst,
                                 int rows, int cols) {
  __shared__ float tile[32][33];
  int mat = blockIdx.z;
  const float* s = src + (size_t)mat * rows * cols;
  float* d = dst + (size_t)mat * rows * cols;
  int c0 = blockIdx.x * 32, r0 = blockIdx.y * 32;
  for (int i = threadIdx.y; i < 32; i += 8)
    tile[i][threadIdx.x] = s[(size_t)(r0 + i) * cols + c0 + threadIdx.x];
  __syncthreads();
  for (int i = threadIdx.y; i < 32; i += 8)
    d[(size_t)(c0 + i) * rows + r0 + threadIdx.x] = tile[threadIdx.x][i];
}

// ---------------- Stockham radix-2 FFT, n=2048, in LDS ----------------
__device__ __forceinline__ float2* fft2048(float2* bufA, float2* bufB,
                                           const float2* __restrict__ tw, int t) {
  float2* src = bufA; float2* dst = bufB;
  for (int stage = 0; stage < 11; ++stage) {
    int s = 1 << stage;
    #pragma unroll
    for (int j = 0; j < 4; ++j) {
      int idx = t + 256 * j;           // 0..1023
      int q = idx & (s - 1);
      int p = idx >> stage;
      float2 a = src[idx];
      float2 b = src[idx + 1024];
      float sr = a.x + b.x, si = a.y + b.y;
      float dr = a.x - b.x, di = a.y - b.y;
      float2 w = tw[p << stage];       // (cos, -sin)
      dst[q + 2 * s * p] = make_float2(sr, si);
      dst[q + 2 * s * p + s] = make_float2(dr * w.x - di * w.y, dr * w.y + di * w.x);
    }
    __syncthreads();
    float2* tmp = src; src = dst; dst = tmp;
  }
  return src;
}

__device__ __forceinline__ void build_tw(float2* tw, int t) {
  #pragma unroll
  for (int j = 0; j < 4; ++j) {
    int i = t + 256 * j;
    float xfrac = (float)i * (1.f / 1024.f);
    tw[i] = make_float2(cospif(xfrac), -sinpif(xfrac));
  }
}

__global__ void rfft_kernel(const float* __restrict__ z, float2* __restrict__ Xf) {
  __shared__ float2 bufA[2048];
  __shared__ float2 bufB[2048];
  __shared__ float2 tw[1024];
  int row = blockIdx.x;            // b*D + d
  int t = threadIdx.x;
  build_tw(tw, t);
  const float* zr = z + (size_t)row * LL;
  #pragma unroll
  for (int j = 0; j < 8; ++j) {
    int i = t + 256 * j;
    bufA[i] = make_float2(zr[i], 0.f);
  }
  __syncthreads();
  float2* res = fft2048(bufA, bufB, tw, t);
  #pragma unroll
  for (int j = 0; j < 5; ++j) {
    int r = t + 256 * j;
    if (r <= 1024) Xf[(size_t)row * RR + r] = res[r];
  }
}

// irfft(F, n=2048) = real( fft( conj(F_full) ) ) / 2048
__global__ void irfft_kernel(const float2* __restrict__ Sf, float* __restrict__ S) {
  __shared__ float2 bufA[2048];
  __shared__ float2 bufB[2048];
  __shared__ float2 tw[1024];
  int row = blockIdx.x;            // b*D + h
  int t = threadIdx.x;
  build_tw(tw, t);
  const float2* fr = Sf + (size_t)row * RR;
  #pragma unroll
  for (int j = 0; j < 8; ++j) {
    int i = t + 256 * j;
    float2 v;
    if (i <= 1024) { v = fr[i]; v.y = -v.y; }   // conj(F[i])
    else           { v = fr[2048 - i]; }        // F[2048-i]
    bufA[i] = v;
  }
  __syncthreads();
  float2* res = fft2048(bufA, bufB, tw, t);
  const float scale = 1.f / 2048.f;
  float* sr = S + (size_t)row * LL;
  #pragma unroll
  for (int j = 0; j < 8; ++j) {
    int i = t + 256 * j;
    sr[i] = res[i].x * scale;
  }
}

// ---------------- spectral mixing ----------------
// Sf[b,h,r] = sum_d Xf[b,d,r] * M[d,h,r],  M = sum_k Theta[k,h,d]*conj(Phi)[k,r]
// Thread: 1 r, 4 h (float4 Theta loads), all 8 b. Block: 64 thr = 8 r x 8 hg.
// Grid (129 r-tiles of 8, 8 h-tiles of 32). d staged in LDS chunks of 32.
__global__ void __launch_bounds__(64)
spectral_kernel(const float2* __restrict__ Xf,
                const float* __restrict__ ThT,   // [K][d][h]
                const float* __restrict__ Phi_re,
                const float* __restrict__ Phi_im,
                float2* __restrict__ Sf) {
  __shared__ float2 xs[BB][32][8];     // 16 KB
  int t = threadIdx.x;                 // 0..63
  int rl = t & 7;
  int hg = t >> 3;                     // 0..7
  int r0 = blockIdx.x << 3;
  int h = (blockIdx.y << 5) + (hg << 2);   // 4 consecutive h's
  int r = r0 + rl;
  int rc = min(r, RR - 1);

  float phr[KK], phim[KK];
  #pragma unroll
  for (int k = 0; k < KK; ++k) {
    phr[k]  = Phi_re[k * RR + rc];
    phim[k] = Phi_im[k * RR + rc];
  }
  float acr[4][BB], aci[4][BB];
  #pragma unroll
  for (int j = 0; j < 4; ++j)
    #pragma unroll
    for (int b = 0; b < BB; ++b) { acr[j][b] = 0.f; aci[j][b] = 0.f; }

  for (int dc = 0; dc < DD; dc += 32) {
    __syncthreads();
    #pragma unroll
    for (int jj = 0; jj < 32; ++jj) {
      int i = t + 64 * jj;             // 0..2047
      int b = i >> 8;
      int dl = (i >> 3) & 31;
      int rr = i & 7;
      xs[b][dl][rr] = Xf[((size_t)(b * DD + dc + dl)) * RR + min(r0 + rr, RR - 1)];
    }
    __syncthreads();
    for (int dl = 0; dl < 32; ++dl) {
      int d = dc + dl;
      const float4* tp = reinterpret_cast<const float4*>(ThT + (size_t)d * DD + h);
      float mre[4] = {0.f, 0.f, 0.f, 0.f};
      float mim[4] = {0.f, 0.f, 0.f, 0.f};
      // k-chunked loads (<=12 float4 live at once), M complete before X pass
      #pragma unroll
      for (int kc = 0; kc < 2; ++kc) {
        float4 th[12];
        #pragma unroll
        for (int kk = 0; kk < 12; ++kk)
          th[kk] = tp[(size_t)(kc * 12 + kk) * (DD * DD / 4)];
        #pragma unroll
        for (int kk = 0; kk < 12; ++kk) {
          int k = kc * 12 + kk;
          float pr = phr[k], pi = phim[k];
          mre[0] += th[kk].x * pr;  mim[0] -= th[kk].x * pi;
          mre[1] += th[kk].y * pr;  mim[1] -= th[kk].y * pi;
          mre[2] += th[kk].z * pr;  mim[2] -= th[kk].z * pi;
          mre[3] += th[kk].w * pr;  mim[3] -= th[kk].w * pi;
        }
      }
      #pragma unroll
      for (int b = 0; b < BB; ++b) {
        float2 xv = xs[b][dl][rl];
        #pragma unroll
        for (int j = 0; j < 4; ++j) {
          acr[j][b] += xv.x * mre[j] - xv.y * mim[j];
          aci[j][b] += xv.x * mim[j] + xv.y * mre[j];
        }
      }
    }
  }
  if (r < RR) {
    #pragma unroll
    for (int j = 0; j < 4; ++j)
      #pragma unroll
      for (int b = 0; b < BB; ++b)
        Sf[((size_t)(b * DD + h + j)) * RR + r] = make_float2(acr[j][b], aci[j][b]);
  }
}

// ---------------- fused MLP + residual, f32 output ----------------
__global__ void mlp_kernel(const float* __restrict__ S, const float* __restrict__ x,
                           const float* __restrict__ W1T, const float* __restrict__ b1,
                           const float* __restrict__ W2T, const float* __restrict__ b2,
                           float* __restrict__ out) {
  __shared__ float s_s[DD][32];
  __shared__ float h_s[128][36];
  int b = blockIdx.y;
  int l0 = blockIdx.x << 5;
  int t = threadIdx.x;
  {
    const float* Sp = S + ((size_t)(b * DD + t)) * LL + l0;
    float4* drow = reinterpret_cast<float4*>(&s_s[t][0]);
    const float4* srow = reinterpret_cast<const float4*>(Sp);
    #pragma unroll
    for (int j = 0; j < 8; ++j) drow[j] = srow[j];
  }
  int h_loc = t >> 1;
  int lhalf = t & 1;
  float acc[32];
  #pragma unroll
  for (int i = 0; i < 32; ++i) acc[i] = 0.f;

  for (int hcBase = 0; hcBase < HH; hcBase += 128) {
    __syncthreads();
    int h = hcBase + h_loc;
    float a[16];
    float bias = b1[h];
    #pragma unroll
    for (int i = 0; i < 16; ++i) a[i] = bias;
    for (int c = 0; c < DD; ++c) {
      float w = W1T[(size_t)c * HH + h];
      const float4* sv4 = reinterpret_cast<const float4*>(&s_s[c][lhalf * 16]);
      #pragma unroll
      for (int j = 0; j < 4; ++j) {
        float4 sv = sv4[j];
        a[j * 4 + 0] += w * sv.x; a[j * 4 + 1] += w * sv.y;
        a[j * 4 + 2] += w * sv.z; a[j * 4 + 3] += w * sv.w;
      }
    }
    #pragma unroll
    for (int i = 0; i < 16; ++i) {
      float v = a[i];
      h_s[h_loc][lhalf * 16 + i] = 0.5f * v * (1.f + erff(v * 0.70710678118654752f));
    }
    __syncthreads();
    for (int hh = 0; hh < 128; ++hh) {
      float w = W2T[(size_t)(hcBase + hh) * DD + t];
      const float4* hv4 = reinterpret_cast<const float4*>(&h_s[hh][0]);
      #pragma unroll
      for (int j = 0; j < 8; ++j) {
        float4 hv = hv4[j];
        acc[j * 4 + 0] += w * hv.x; acc[j * 4 + 1] += w * hv.y;
        acc[j * 4 + 2] += w * hv.z; acc[j * 4 + 3] += w * hv.w;
      }
    }
  }
  const float* xp = x + ((size_t)(b * DD + t)) * LL + l0;
  float* op = out + ((size_t)(b * DD + t)) * LL + l0;
  float bb2 = b2[t];
  #pragma unroll
  for (int j = 0; j < 8; ++j) {
    float4 xv = reinterpret_cast<const float4*>(xp)[j];
    float4 o;
    o.x = xv.x + bb2 + acc[j * 4 + 0];
    o.y = xv.y + bb2 + acc[j * 4 + 1];
    o.z = xv.z + bb2 + acc[j * 4 + 2];
    o.w = xv.w + bb2 + acc[j * 4 + 3];
    reinterpret_cast<float4*>(op)[j] = o;
  }
}

extern "C" void kernel_launch(void* const* d_in, const int* in_sizes, int n_in,
                              void* d_out, int out_size, void* d_ws, size_t ws_size,
                              hipStream_t stream) {
  const float* x      = (const float*)d_in[0];
  const float* Phi_re = (const float*)d_in[1];
  const float* Phi_im = (const float*)d_in[2];
  const float* Theta  = (const float*)d_in[3];
  const float* gamma  = (const float*)d_in[4];
  const float* beta   = (const float*)d_in[5];
  const float* W1     = (const float*)d_in[6];
  const float* b1     = (const float*)d_in[7];
  const float* W2     = (const float*)d_in[8];
  const float* b2     = (const float*)d_in[9];

  float* ws = (float*)d_ws;
  float*  z   = ws;                          // 4,194,304 floats (reused for S)
  float2* Xf  = (float2*)(ws + 4194304);     // 2,099,200 float2
  float2* Sf  = (float2*)(ws + 8392704);     // 2,099,200 float2
  float*  ThT = ws + 12591104;               // 1,572,864
  float*  W1T = ws + 14163968;               // 131,072
  float*  W2T = ws + 14295040;               // 131,072

  ln_kernel<<<dim3(BB * (LL / 64)), 256, 0, stream>>>(x, gamma, beta, z);
  transpose_kernel<<<dim3(8, 8, 24), dim3(32, 8), 0, stream>>>(Theta, ThT, 256, 256);
  transpose_kernel<<<dim3(8, 16, 1), dim3(32, 8), 0, stream>>>(W1, W1T, 512, 256);
  transpose_kernel<<<dim3(16, 8, 1), dim3(32, 8), 0, stream>>>(W2, W2T, 256, 512);
  rfft_kernel<<<dim3(BB * DD), 256, 0, stream>>>(z, Xf);
  spectral_kernel<<<dim3(129, 8), 64, 0, stream>>>(Xf, ThT, Phi_re, Phi_im, Sf);
  irfft_kernel<<<dim3(BB * DD), 256, 0, stream>>>(Sf, z);      // S -> z buffer
  mlp_kernel<<<dim3(LL / 32, BB), 256, 0, stream>>>(z, x, W1T, b1, W2T, b2,
                                                    (float*)d_out);
}